// Round 23
// baseline (73.857 us; speedup 1.0000x reference)
//
#include <hip/hip_runtime.h>

namespace {
constexpr int FB = 9;
constexpr int FD = 1152;
constexpr float LN_EPS = 1e-5f;
constexpr int NT = 512;   // 8 waves, 32 tokens/block

typedef __attribute__((ext_vector_type(8))) short short8v;
typedef __attribute__((ext_vector_type(4))) float float4v;

// ---- ws layout ----
constexpr int WSA_F  = 0;      // A[9][384]
constexpr int WSC_F  = 3456;   // C[9][384]
constexpr int COEF_F = 6912;   // [36][40] score coeffs
constexpr int BF_F   = 8352;   // fused bias [384]
constexpr int OPA_F  = 8736;   // OPA[72][128]
constexpr int P2F_B  = 71808;  // proj2 frags (65536 B)
constexpr int WTA_B  = 137344; // WTA frags [24nt*21ks][64][8] bf16 (516096 B)

// ---- LDS (main), bytes ----
constexpr int LDS_BYTES = 49920;
constexpr int L_LNP  = 16384;
constexpr int L_GATE = 17408;
constexpr int L_COEF = 43008;
constexpr int L_SX   = 48768;

// K1 grid split: ACO(9) + bias(384) + p2f(64)
constexpr int NB_ACO  = 9;
constexpr int NB_BIAS = 384;
constexpr int NB_P2   = 64;
// K2 grid split: WTA(72) + coef(1)
constexpr int NB_WTA  = 72;

__device__ __forceinline__ unsigned short f2bf(float f) {
    unsigned u = __builtin_bit_cast(unsigned, f);
    u += 0x7FFFu + ((u >> 16) & 1u);
    return (unsigned short)(u >> 16);
}
__device__ __forceinline__ unsigned pkr(float lo, float hi) {
    const unsigned a = __builtin_bit_cast(unsigned, lo) + 0x8000u;
    const unsigned b = __builtin_bit_cast(unsigned, hi) + 0x8000u;
    return __builtin_amdgcn_perm(b, a, 0x07060302u);
}
// fast GELU (tanh form, guarded): err <= ~1e-3 on h
__device__ __forceinline__ float gelu_f(float v) {
    float z = 0.7978845608f * (v + 0.044715f * v * v * v);
    z = fminf(fmaxf(z, -15.f), 15.f);
    const float e = __expf(2.f * z);
    const float th = (e - 1.f) / (e + 1.f);
    return 0.5f * v * (1.f + th);
}
#define MFMA16x32(a, b, c) __builtin_amdgcn_mfma_f32_16x16x32_bf16(a, b, c, 0, 0, 0)
} // namespace

// ---------------- K1: ACO + bias + p2f (457 independent blocks) ----------------
__global__ __launch_bounds__(512)
void precompK1(const float* __restrict__ bW, const float* __restrict__ bb,
               const float* __restrict__ fp, const float* __restrict__ ipw,
               const float* __restrict__ ipb, const float* __restrict__ opw,
               const float* __restrict__ gw, const float* __restrict__ gb,
               const float* __restrict__ p1w, const float* __restrict__ p1b,
               const float* __restrict__ opb, const float* __restrict__ p2w,
               unsigned short* __restrict__ p2f, float* __restrict__ ws)
{
    __shared__ float smem[512];
    const int bid = blockIdx.x, t = threadIdx.x;
    if (bid < NB_ACO) {
        float* sw  = smem;
        float* sc  = smem + 128;
        float* sAv = smem + 256;
        float* sCv = smem + 384;
        const int f = bid;
        if (t < 128) { sw[t] = bW[f * 128 + t]; sc[t] = bb[f * 128 + t] + fp[f * 128 + t]; }
        __syncthreads();
        if (t < 384) {
            const float* row = ipw + (size_t)t * 128;
            float a = 0.f, c = 0.f;
            for (int k = 0; k < 128; k += 4) {
                const float4 w = *(const float4*)(row + k);
                a += sw[k]*w.x + sw[k+1]*w.y + sw[k+2]*w.z + sw[k+3]*w.w;
                c += sc[k]*w.x + sc[k+1]*w.y + sc[k+2]*w.z + sc[k+3]*w.w;
            }
            const float cb = c + ipb[t];
            ws[WSA_F + f * 384 + t] = a;
            ws[WSC_F + f * 384 + t] = cb;
            if (t >= 256) { sAv[t - 256] = a; sCv[t - 256] = cb; }
        }
        __syncthreads();
        for (int d = t; d < 1024; d += 512) {
            const int r = d >> 7, j = d & 127;
            const int h = r >> 1, which = r & 1;
            const float* src = (which ? sCv : sAv) + h * 32;
            const float* op = opw + (size_t)j * 128 + h * 32;
            float s = 0.f;
            #pragma unroll
            for (int ii = 0; ii < 32; ++ii) s += op[ii] * src[ii];
            const int kk = which ? (9 + f) : f;
            ws[OPA_F + (h * 18 + kk) * 128 + j] = s;
        }
    } else if (bid < NB_ACO + NB_BIAS) {
        const int e = bid - NB_ACO;
        const float* Win = (e < 128) ? gw + (size_t)e * FD : p1w + (size_t)(e - 128) * FD;
        float acc = 0.f;
        for (int m = t; m < FD; m += 512) acc += Win[m] * opb[m & 127];
        #pragma unroll
        for (int off = 32; off > 0; off >>= 1) acc += __shfl_xor(acc, off);
        const int lane = t & 63, wid = t >> 6;
        if (lane == 0) smem[wid] = acc;
        __syncthreads();
        if (t == 0) {
            float s = (e < 128) ? gb[e] : p1b[e - 128];
            #pragma unroll
            for (int w = 0; w < 8; ++w) s += smem[w];
            ws[BF_F + e] = s;
        }
    } else {
        const int id = (bid - NB_ACO - NB_BIAS) * 512 + t;   // 32768
        const int j = id & 7, lane = (id >> 3) & 63, ks = (id >> 9) & 7, nt = id >> 12;
        const int i = nt * 16 + (lane & 15);
        const int r = ks * 32 + (lane >> 4) * 8 + j;
        p2f[id] = f2bf(p2w[i * 256 + r]);
    }
}

// ---------------- K2: WTA + score coeffs (dep: ACO) ----------------
__global__ __launch_bounds__(512)
void precompK2(const float* __restrict__ gw, const float* __restrict__ p1w,
               const float* __restrict__ wsf,
               unsigned short* __restrict__ wta, float* __restrict__ ws)
{
    __shared__ float smem[128 * 73 + 128 * 49];   // 62464 B
    const int bid = blockIdx.x, t = threadIdx.x;
    if (bid < NB_WTA) {
        float* s_opaT = smem;              // [j][73]
        float* s_winT = smem + 128 * 73;   // [j][49]
        const int fq = bid % 9, oct = bid / 9;
        const int e0 = oct * 48;
        for (int i = t; i < 9216; i += 512) {
            const int r = i >> 7, j = i & 127;
            s_opaT[j * 73 + r] = wsf[OPA_F + i];
        }
        for (int i = t; i < 6144; i += 512) {
            const int el = i >> 7, j = i & 127;
            const int e = e0 + el;
            const float* Win = (e < 128) ? gw + (size_t)e * FD : p1w + (size_t)(e - 128) * FD;
            s_winT[j * 49 + el] = Win[fq * 128 + j];
        }
        __syncthreads();
        for (int d = t; d < 3456; d += 512) {
            const int el = d / 72, r = d - el * 72;
            const int e = e0 + el;
            float acc = 0.f;
            #pragma unroll 8
            for (int j = 0; j < 128; ++j)
                acc += s_winT[j * 49 + el] * s_opaT[j * 73 + r];
            const int h = r / 18, kk = r - h * 18;
            const int K = (h * 9 + fq) * 18 + kk;
            const int ks = K >> 5, slot = K & 31;
            const int lane = (e & 15) + 16 * (slot >> 3);
            wta[((size_t)((e >> 4) * 21 + ks) * 64 + lane) * 8 + (slot & 7)] = f2bf(acc);
        }
        if (fq == 0) {
            for (int d = t; d < 48 * 24; d += 512) {
                const int el = d / 24, Kp = 648 + d % 24;
                const int e = e0 + el;
                const int ks = Kp >> 5, slot = Kp & 31;
                const int lane = (e & 15) + 16 * (slot >> 3);
                wta[((size_t)((e >> 4) * 21 + ks) * 64 + lane) * 8 + (slot & 7)] = 0;
            }
        }
    } else {
        if (t >= 324) return;
        const int h = t / 81, r = t % 81, fq = r / 9, fk = r % 9;
        const float* A = wsf + WSA_F;
        const float* C = wsf + WSC_F;
        const float* aq = A + fq * 384 + h * 32;
        const float* ak = A + fk * 384 + 128 + h * 32;
        const float* cq = C + fq * 384 + h * 32;
        const float* ck = C + fk * 384 + 128 + h * 32;
        float s2 = 0.f, s1q = 0.f, s1k = 0.f, s0 = 0.f;
        #pragma unroll
        for (int d = 0; d < 32; ++d) {
            s2  += aq[d] * ak[d];
            s1q += aq[d] * ck[d];
            s1k += cq[d] * ak[d];
            s0  += cq[d] * ck[d];
        }
        const float sc = 0.17677669529663687f;
        float* row = ws + COEF_F + (h * 9 + fq) * 40;
        row[fk]      = s2  * sc;
        row[10 + fk] = s1q * sc;
        row[20 + fk] = s1k * sc;
        row[30 + fk] = s0  * sc;
    }
}

// ---------------- main: R22 + depth-2 double-buffered B prefetch ----------------
__global__ __launch_bounds__(NT, 4)
void fba_main(const float* __restrict__ x, const float* __restrict__ p2b,
              const float* __restrict__ lng, const float* __restrict__ lnb,
              const float* __restrict__ wsf,
              const unsigned short* __restrict__ p2frag,
              const unsigned short* __restrict__ wta,
              float* __restrict__ out)
{
    __shared__ float4 lds4[LDS_BYTES / 16];
    char* lds = (char*)lds4;
    unsigned short* hfrag = (unsigned short*)lds;            // alias (tail)
    float* lnp = (float*)(lds + L_LNP);                      // alias (tail)
    unsigned short* gateb = (unsigned short*)(lds + L_GATE); // alias (tail)
    float* scoef = (float*)(lds + L_COEF);
    float* sx    = (float*)(lds + L_SX);

    const int t = threadIdx.x, lane = t & 63, wid = t >> 6;
    const int col = lane & 15, rg = lane >> 4;
    const int n0 = blockIdx.x * 32;

    for (int i = t; i < 1440; i += NT) scoef[i] = wsf[COEF_F + i];
    for (int i = t; i < 288;  i += NT) sx[i] = x[(size_t)n0 * FB + i];
    if (t < 128) *(float4*)(lds + 40960 + t * 16) = float4{0.f, 0.f, 0.f, 0.f};
    __syncthreads();

    // ---- Phase A ----
    for (int id = t; id < 1152; id += NT) {
        const int p = id >> 5, g = id & 31;
        const int fq = p % 9;
        const float* cf = scoef + p * 40;
        const float* xg = sx + g * FB;
        const float xq = xg[fq];
        float sc[9];
        float m = -1e30f;
        #pragma unroll
        for (int fk = 0; fk < 9; ++fk) {
            const float xk = xg[fk];
            const float v = (cf[fk] * xk + cf[10 + fk]) * xq + cf[20 + fk] * xk + cf[30 + fk];
            sc[fk] = v;
            m = fmaxf(m, v);
        }
        float sum = 0.f;
        #pragma unroll
        for (int fk = 0; fk < 9; ++fk) { sc[fk] = __expf(sc[fk] - m); sum += sc[fk]; }
        const float inv = 1.f / sum;
        float v[18];
        #pragma unroll
        for (int fk = 0; fk < 9; ++fk) {
            const float a = sc[fk] * inv;
            v[fk]     = a * xg[fk];
            v[9 + fk] = a;
        }
        const int mg = g >> 4, gl = g & 15;
        const int K0 = p * 18;
        #pragma unroll
        for (int qq = 0; qq < 9; ++qq) {
            const int K = K0 + 2 * qq;
            const int ks = K >> 5, slot = K & 31;
            const int row = ks * 2 + mg;
            const int u = gl + 16 * (slot >> 3);
            *(unsigned*)(lds + row * 1024 + u * 16 + (slot & 7) * 2) = pkr(v[2 * qq], v[2 * qq + 1]);
        }
    }
    __syncthreads();

    // ---- K-loop: depth-2 double-buffered B prefetch + setprio MFMA cluster.
    // Full unroll keeps buffer parity compile-time (no scratch). ----
    const int ng = wid;
    float4v acc0[3], acc1[3];
    #pragma unroll
    for (int q = 0; q < 3; ++q) {
        const float b = wsf[BF_F + (ng * 3 + q) * 16 + col];
        acc0[q] = float4v{b, b, b, b};
        acc1[q] = float4v{b, b, b, b};
    }
    const unsigned short* bbase = wta + (size_t)(ng * 3) * 21 * 512 + lane * 8;
    #define BLOAD(ks, q) (*(const short8v*)(bbase + ((size_t)(q) * 21 + (ks)) * 512))
    short8v bq[2][3];
    bq[0][0] = BLOAD(0, 0); bq[0][1] = BLOAD(0, 1); bq[0][2] = BLOAD(0, 2);
    bq[1][0] = BLOAD(1, 0); bq[1][1] = BLOAD(1, 1); bq[1][2] = BLOAD(1, 2);
    #pragma unroll
    for (int ks = 0; ks < 21; ++ks) {
        const int pb = ks & 1;                 // compile-time after unroll
        const short8v c0 = bq[pb][0], c1 = bq[pb][1], c2 = bq[pb][2];
        if (ks + 2 < 21) {
            bq[pb][0] = BLOAD(ks + 2, 0);
            bq[pb][1] = BLOAD(ks + 2, 1);
            bq[pb][2] = BLOAD(ks + 2, 2);
        }
        const short8v a0 = *(const short8v*)(lds + ((ks * 2 + 0) * 64 + lane) * 16);
        const short8v a1 = *(const short8v*)(lds + ((ks * 2 + 1) * 64 + lane) * 16);
        __builtin_amdgcn_s_setprio(1);
        acc0[0] = MFMA16x32(a0, c0, acc0[0]);
        acc1[0] = MFMA16x32(a1, c0, acc1[0]);
        acc0[1] = MFMA16x32(a0, c1, acc0[1]);
        acc1[1] = MFMA16x32(a1, c1, acc1[1]);
        acc0[2] = MFMA16x32(a0, c2, acc0[2]);
        acc1[2] = MFMA16x32(a1, c2, acc1[2]);
        __builtin_amdgcn_s_setprio(0);
    }
    #undef BLOAD
    __syncthreads();

    // ---- epilogue: gate -> unorm16 LDS, h -> hfrag bf16 (fast GELU) ----
    #pragma unroll
    for (int q = 0; q < 3; ++q) {
        const int e = (ng * 3 + q) * 16 + col;
        #pragma unroll
        for (int j = 0; j < 4; ++j) {
            #pragma unroll
            for (int mi = 0; mi < 2; ++mi) {
                const float vv = (mi == 0) ? acc0[q][j] : acc1[q][j];
                const int token = mi * 16 + rg * 4 + j;
                if (e < 128) {
                    const float gv = 1.f / (1.f + __expf(-vv));
                    gateb[token * 128 + e] = (unsigned short)(gv * 65535.f + 0.5f);
                } else {
                    const int rr = e - 128;
                    const float hv = gelu_f(vv);
                    hfrag[mi * 4096 + (rr >> 5) * 512 + (rg * 4 + j + 16 * ((rr >> 3) & 3)) * 8 + (rr & 7)] = f2bf(hv);
                }
            }
        }
    }
    __syncthreads();

    // ---- proj2 distributed over all 8 waves ----
    {
        const int mm = wid & 1, nh = wid >> 1;
        float4v y[2];
        float lg[2], lb[2];
        #pragma unroll
        for (int nti = 0; nti < 2; ++nti) {
            const int i = (nh * 2 + nti) * 16 + col;
            const float b = p2b[i];
            y[nti] = float4v{b, b, b, b};
            lg[nti] = lng[i];
            lb[nti] = lnb[i];
        }
        #pragma unroll
        for (int ks = 0; ks < 8; ++ks) {
            const short8v ah = *(const short8v*)(hfrag + mm * 4096 + ks * 512 + lane * 8);
            #pragma unroll
            for (int nti = 0; nti < 2; ++nti) {
                const short8v bw = *(const short8v*)(p2frag + (((nh * 2 + nti) * 8 + ks) * 64 + lane) * 8);
                y[nti] = MFMA16x32(ah, bw, y[nti]);
            }
        }
        #pragma unroll
        for (int j = 0; j < 4; ++j) {
            const int token = mm * 16 + rg * 4 + j;
            float s = y[0][j] + y[1][j];
            float qq = y[0][j] * y[0][j] + y[1][j] * y[1][j];
            s  += __shfl_xor(s, 1);  s  += __shfl_xor(s, 2);
            s  += __shfl_xor(s, 4);  s  += __shfl_xor(s, 8);
            qq += __shfl_xor(qq, 1); qq += __shfl_xor(qq, 2);
            qq += __shfl_xor(qq, 4); qq += __shfl_xor(qq, 8);
            if (col == 0) {
                lnp[token * 8 + nh * 2]     = s;
                lnp[token * 8 + nh * 2 + 1] = qq;
            }
        }
        __syncthreads();
        #pragma unroll
        for (int j = 0; j < 4; ++j) {
            const int token = mm * 16 + rg * 4 + j;
            const float s  = lnp[token * 8] + lnp[token * 8 + 2] + lnp[token * 8 + 4] + lnp[token * 8 + 6];
            const float qq = lnp[token * 8 + 1] + lnp[token * 8 + 3] + lnp[token * 8 + 5] + lnp[token * 8 + 7];
            const float mu = s * (1.f / 128.f);
            const float var = qq * (1.f / 128.f) - mu * mu;
            const float inv = rsqrtf(var + LN_EPS);
            float* op = out + (size_t)(n0 + token) * 128;
            #pragma unroll
            for (int nti = 0; nti < 2; ++nti) {
                const int i = (nh * 2 + nti) * 16 + col;
                const float gv = (float)gateb[token * 128 + i] * (1.f / 65535.f);
                op[i] = ((y[nti][j] - mu) * inv * lg[nti] + lb[nti]) * gv;
            }
        }
    }
}

extern "C" void kernel_launch(void* const* d_in, const int* in_sizes, int n_in,
                              void* d_out, int out_size, void* d_ws, size_t ws_size,
                              hipStream_t stream)
{
    const float* x          = (const float*)d_in[0];
    const float* band_W     = (const float*)d_in[1];
    const float* band_b     = (const float*)d_in[2];
    const float* freq_pos   = (const float*)d_in[3];
    const float* in_proj_w  = (const float*)d_in[4];
    const float* in_proj_b  = (const float*)d_in[5];
    const float* out_proj_w = (const float*)d_in[6];
    const float* out_proj_b = (const float*)d_in[7];
    const float* gate_w     = (const float*)d_in[8];
    const float* gate_b     = (const float*)d_in[9];
    const float* proj1_w    = (const float*)d_in[10];
    const float* proj1_b    = (const float*)d_in[11];
    const float* proj2_w    = (const float*)d_in[12];
    const float* proj2_b    = (const float*)d_in[13];
    const float* ln_g       = (const float*)d_in[14];
    const float* ln_b       = (const float*)d_in[15];
    float* outp = (float*)d_out;

    float* wsf = (float*)d_ws;
    unsigned short* p2f = (unsigned short*)((char*)d_ws + P2F_B);
    unsigned short* wta = (unsigned short*)((char*)d_ws + WTA_B);

    const int Ntok = in_sizes[0] / FB;   // 32768
    const int nblk = Ntok / 32;          // 1024

    hipLaunchKernelGGL(precompK1, dim3(NB_ACO + NB_BIAS + NB_P2), dim3(512), 0, stream,
                       band_W, band_b, freq_pos, in_proj_w, in_proj_b, out_proj_w,
                       gate_w, gate_b, proj1_w, proj1_b, out_proj_b, proj2_w, p2f, wsf);
    hipLaunchKernelGGL(precompK2, dim3(NB_WTA + 1), dim3(512), 0, stream,
                       gate_w, proj1_w, wsf, wta, wsf);
    hipLaunchKernelGGL(fba_main,  dim3(nblk), dim3(NT), 0, stream,
                       x, proj2_b, ln_g, ln_b, wsf, p2f, wta, outp);
}

// Round 24
// 71.315 us; speedup vs baseline: 1.0356x; 1.0356x over previous
//
#include <hip/hip_runtime.h>

namespace {
constexpr int FB = 9;
constexpr int FD = 1152;
constexpr float LN_EPS = 1e-5f;
constexpr int NT = 512;   // 8 waves, 32 tokens/block

typedef __attribute__((ext_vector_type(8))) short short8v;
typedef __attribute__((ext_vector_type(4))) float float4v;

// ---- ws layout ----
constexpr int WSA_F  = 0;      // A[9][384]
constexpr int WSC_F  = 3456;   // C[9][384]
constexpr int COEF_F = 6912;   // [36][40] score coeffs
constexpr int BF_F   = 8352;   // fused bias [384]
constexpr int OPA_F  = 8736;   // OPA[72][128]
constexpr int P2F_B  = 71808;  // proj2 frags (65536 B)
constexpr int WTA_B  = 137344; // WTA frags [24nt*21ks][64][8] bf16 (516096 B)

// ---- LDS (main), bytes ----
constexpr int LDS_BYTES = 49920;
constexpr int L_LNP  = 16384;
constexpr int L_GATE = 17408;
constexpr int L_COEF = 43008;
constexpr int L_SX   = 48768;

// K1 grid split: ACO(9) + bias(384) + p2f(64)
constexpr int NB_ACO  = 9;
constexpr int NB_BIAS = 384;
constexpr int NB_P2   = 64;
// K2 grid split: WTA(72) + coef(1)
constexpr int NB_WTA  = 72;

__device__ __forceinline__ unsigned short f2bf(float f) {
    unsigned u = __builtin_bit_cast(unsigned, f);
    u += 0x7FFFu + ((u >> 16) & 1u);
    return (unsigned short)(u >> 16);
}
__device__ __forceinline__ unsigned pkr(float lo, float hi) {
    const unsigned a = __builtin_bit_cast(unsigned, lo) + 0x8000u;
    const unsigned b = __builtin_bit_cast(unsigned, hi) + 0x8000u;
    return __builtin_amdgcn_perm(b, a, 0x07060302u);
}
// fast GELU (tanh form, guarded): err <= ~1e-3 on h
__device__ __forceinline__ float gelu_f(float v) {
    float z = 0.7978845608f * (v + 0.044715f * v * v * v);
    z = fminf(fmaxf(z, -15.f), 15.f);
    const float e = __expf(2.f * z);
    const float th = (e - 1.f) / (e + 1.f);
    return 0.5f * v * (1.f + th);
}
#define MFMA16x32(a, b, c) __builtin_amdgcn_mfma_f32_16x16x32_bf16(a, b, c, 0, 0, 0)
} // namespace

// ---------------- K1: ACO + bias + p2f (457 independent blocks) ----------------
__global__ __launch_bounds__(512)
void precompK1(const float* __restrict__ bW, const float* __restrict__ bb,
               const float* __restrict__ fp, const float* __restrict__ ipw,
               const float* __restrict__ ipb, const float* __restrict__ opw,
               const float* __restrict__ gw, const float* __restrict__ gb,
               const float* __restrict__ p1w, const float* __restrict__ p1b,
               const float* __restrict__ opb, const float* __restrict__ p2w,
               unsigned short* __restrict__ p2f, float* __restrict__ ws)
{
    __shared__ float smem[512];
    const int bid = blockIdx.x, t = threadIdx.x;
    if (bid < NB_ACO) {
        float* sw  = smem;
        float* sc  = smem + 128;
        float* sAv = smem + 256;
        float* sCv = smem + 384;
        const int f = bid;
        if (t < 128) { sw[t] = bW[f * 128 + t]; sc[t] = bb[f * 128 + t] + fp[f * 128 + t]; }
        __syncthreads();
        if (t < 384) {
            const float* row = ipw + (size_t)t * 128;
            float a = 0.f, c = 0.f;
            for (int k = 0; k < 128; k += 4) {
                const float4 w = *(const float4*)(row + k);
                a += sw[k]*w.x + sw[k+1]*w.y + sw[k+2]*w.z + sw[k+3]*w.w;
                c += sc[k]*w.x + sc[k+1]*w.y + sc[k+2]*w.z + sc[k+3]*w.w;
            }
            const float cb = c + ipb[t];
            ws[WSA_F + f * 384 + t] = a;
            ws[WSC_F + f * 384 + t] = cb;
            if (t >= 256) { sAv[t - 256] = a; sCv[t - 256] = cb; }
        }
        __syncthreads();
        for (int d = t; d < 1024; d += 512) {
            const int r = d >> 7, j = d & 127;
            const int h = r >> 1, which = r & 1;
            const float* src = (which ? sCv : sAv) + h * 32;
            const float* op = opw + (size_t)j * 128 + h * 32;
            float s = 0.f;
            #pragma unroll
            for (int ii = 0; ii < 32; ++ii) s += op[ii] * src[ii];
            const int kk = which ? (9 + f) : f;
            ws[OPA_F + (h * 18 + kk) * 128 + j] = s;
        }
    } else if (bid < NB_ACO + NB_BIAS) {
        const int e = bid - NB_ACO;
        const float* Win = (e < 128) ? gw + (size_t)e * FD : p1w + (size_t)(e - 128) * FD;
        float acc = 0.f;
        for (int m = t; m < FD; m += 512) acc += Win[m] * opb[m & 127];
        #pragma unroll
        for (int off = 32; off > 0; off >>= 1) acc += __shfl_xor(acc, off);
        const int lane = t & 63, wid = t >> 6;
        if (lane == 0) smem[wid] = acc;
        __syncthreads();
        if (t == 0) {
            float s = (e < 128) ? gb[e] : p1b[e - 128];
            #pragma unroll
            for (int w = 0; w < 8; ++w) s += smem[w];
            ws[BF_F + e] = s;
        }
    } else {
        const int id = (bid - NB_ACO - NB_BIAS) * 512 + t;   // 32768
        const int j = id & 7, lane = (id >> 3) & 63, ks = (id >> 9) & 7, nt = id >> 12;
        const int i = nt * 16 + (lane & 15);
        const int r = ks * 32 + (lane >> 4) * 8 + j;
        p2f[id] = f2bf(p2w[i * 256 + r]);
    }
}

// ---------------- K2: WTA + score coeffs (dep: ACO) ----------------
__global__ __launch_bounds__(512)
void precompK2(const float* __restrict__ gw, const float* __restrict__ p1w,
               const float* __restrict__ wsf,
               unsigned short* __restrict__ wta, float* __restrict__ ws)
{
    __shared__ float smem[128 * 73 + 128 * 49];   // 62464 B
    const int bid = blockIdx.x, t = threadIdx.x;
    if (bid < NB_WTA) {
        float* s_opaT = smem;              // [j][73]
        float* s_winT = smem + 128 * 73;   // [j][49]
        const int fq = bid % 9, oct = bid / 9;
        const int e0 = oct * 48;
        for (int i = t; i < 9216; i += 512) {
            const int r = i >> 7, j = i & 127;
            s_opaT[j * 73 + r] = wsf[OPA_F + i];
        }
        for (int i = t; i < 6144; i += 512) {
            const int el = i >> 7, j = i & 127;
            const int e = e0 + el;
            const float* Win = (e < 128) ? gw + (size_t)e * FD : p1w + (size_t)(e - 128) * FD;
            s_winT[j * 49 + el] = Win[fq * 128 + j];
        }
        __syncthreads();
        for (int d = t; d < 3456; d += 512) {
            const int el = d / 72, r = d - el * 72;
            const int e = e0 + el;
            float acc = 0.f;
            #pragma unroll 8
            for (int j = 0; j < 128; ++j)
                acc += s_winT[j * 49 + el] * s_opaT[j * 73 + r];
            const int h = r / 18, kk = r - h * 18;
            const int K = (h * 9 + fq) * 18 + kk;
            const int ks = K >> 5, slot = K & 31;
            const int lane = (e & 15) + 16 * (slot >> 3);
            wta[((size_t)((e >> 4) * 21 + ks) * 64 + lane) * 8 + (slot & 7)] = f2bf(acc);
        }
        if (fq == 0) {
            for (int d = t; d < 48 * 24; d += 512) {
                const int el = d / 24, Kp = 648 + d % 24;
                const int e = e0 + el;
                const int ks = Kp >> 5, slot = Kp & 31;
                const int lane = (e & 15) + 16 * (slot >> 3);
                wta[((size_t)((e >> 4) * 21 + ks) * 64 + lane) * 8 + (slot & 7)] = 0;
            }
        }
    } else {
        if (t >= 324) return;
        const int h = t / 81, r = t % 81, fq = r / 9, fk = r % 9;
        const float* A = wsf + WSA_F;
        const float* C = wsf + WSC_F;
        const float* aq = A + fq * 384 + h * 32;
        const float* ak = A + fk * 384 + 128 + h * 32;
        const float* cq = C + fq * 384 + h * 32;
        const float* ck = C + fk * 384 + 128 + h * 32;
        float s2 = 0.f, s1q = 0.f, s1k = 0.f, s0 = 0.f;
        #pragma unroll
        for (int d = 0; d < 32; ++d) {
            s2  += aq[d] * ak[d];
            s1q += aq[d] * ck[d];
            s1k += cq[d] * ak[d];
            s0  += cq[d] * ck[d];
        }
        const float sc = 0.17677669529663687f;
        float* row = ws + COEF_F + (h * 9 + fq) * 40;
        row[fk]      = s2  * sc;
        row[10 + fk] = s1q * sc;
        row[20 + fk] = s1k * sc;
        row[30 + fk] = s0  * sc;
    }
}

// ---------------- main: R22 (verified best) ----------------
__global__ __launch_bounds__(NT, 4)
void fba_main(const float* __restrict__ x, const float* __restrict__ p2b,
              const float* __restrict__ lng, const float* __restrict__ lnb,
              const float* __restrict__ wsf,
              const unsigned short* __restrict__ p2frag,
              const unsigned short* __restrict__ wta,
              float* __restrict__ out)
{
    __shared__ float4 lds4[LDS_BYTES / 16];
    char* lds = (char*)lds4;
    unsigned short* hfrag = (unsigned short*)lds;            // alias (tail)
    float* lnp = (float*)(lds + L_LNP);                      // alias (tail)
    unsigned short* gateb = (unsigned short*)(lds + L_GATE); // alias (tail)
    float* scoef = (float*)(lds + L_COEF);
    float* sx    = (float*)(lds + L_SX);

    const int t = threadIdx.x, lane = t & 63, wid = t >> 6;
    const int col = lane & 15, rg = lane >> 4;
    const int n0 = blockIdx.x * 32;

    for (int i = t; i < 1440; i += NT) scoef[i] = wsf[COEF_F + i];
    for (int i = t; i < 288;  i += NT) sx[i] = x[(size_t)n0 * FB + i];
    if (t < 128) *(float4*)(lds + 40960 + t * 16) = float4{0.f, 0.f, 0.f, 0.f};
    __syncthreads();

    // ---- Phase A ----
    for (int id = t; id < 1152; id += NT) {
        const int p = id >> 5, g = id & 31;
        const int fq = p % 9;
        const float* cf = scoef + p * 40;
        const float* xg = sx + g * FB;
        const float xq = xg[fq];
        float sc[9];
        float m = -1e30f;
        #pragma unroll
        for (int fk = 0; fk < 9; ++fk) {
            const float xk = xg[fk];
            const float v = (cf[fk] * xk + cf[10 + fk]) * xq + cf[20 + fk] * xk + cf[30 + fk];
            sc[fk] = v;
            m = fmaxf(m, v);
        }
        float sum = 0.f;
        #pragma unroll
        for (int fk = 0; fk < 9; ++fk) { sc[fk] = __expf(sc[fk] - m); sum += sc[fk]; }
        const float inv = 1.f / sum;
        float v[18];
        #pragma unroll
        for (int fk = 0; fk < 9; ++fk) {
            const float a = sc[fk] * inv;
            v[fk]     = a * xg[fk];
            v[9 + fk] = a;
        }
        const int mg = g >> 4, gl = g & 15;
        const int K0 = p * 18;
        #pragma unroll
        for (int qq = 0; qq < 9; ++qq) {
            const int K = K0 + 2 * qq;
            const int ks = K >> 5, slot = K & 31;
            const int row = ks * 2 + mg;
            const int u = gl + 16 * (slot >> 3);
            *(unsigned*)(lds + row * 1024 + u * 16 + (slot & 7) * 2) = pkr(v[2 * qq], v[2 * qq + 1]);
        }
    }
    __syncthreads();

    // ---- K-loop: depth-1 prefetch + setprio over MFMA cluster ----
    const int ng = wid;
    float4v acc0[3], acc1[3];
    #pragma unroll
    for (int q = 0; q < 3; ++q) {
        const float b = wsf[BF_F + (ng * 3 + q) * 16 + col];
        acc0[q] = float4v{b, b, b, b};
        acc1[q] = float4v{b, b, b, b};
    }
    const unsigned short* bbase = wta + (size_t)(ng * 3) * 21 * 512 + lane * 8;
    #define BLOAD(ks, q) (*(const short8v*)(bbase + ((size_t)(q) * 21 + (ks)) * 512))
    short8v cur0 = BLOAD(0, 0), cur1 = BLOAD(0, 1), cur2 = BLOAD(0, 2);
    #pragma unroll 4
    for (int ks = 0; ks < 20; ++ks) {
        const short8v nxt0 = BLOAD(ks + 1, 0);
        const short8v nxt1 = BLOAD(ks + 1, 1);
        const short8v nxt2 = BLOAD(ks + 1, 2);
        const short8v a0 = *(const short8v*)(lds + ((ks * 2 + 0) * 64 + lane) * 16);
        const short8v a1 = *(const short8v*)(lds + ((ks * 2 + 1) * 64 + lane) * 16);
        __builtin_amdgcn_s_setprio(1);
        acc0[0] = MFMA16x32(a0, cur0, acc0[0]);
        acc1[0] = MFMA16x32(a1, cur0, acc1[0]);
        acc0[1] = MFMA16x32(a0, cur1, acc0[1]);
        acc1[1] = MFMA16x32(a1, cur1, acc1[1]);
        acc0[2] = MFMA16x32(a0, cur2, acc0[2]);
        acc1[2] = MFMA16x32(a1, cur2, acc1[2]);
        __builtin_amdgcn_s_setprio(0);
        cur0 = nxt0; cur1 = nxt1; cur2 = nxt2;
    }
    {
        const short8v a0 = *(const short8v*)(lds + ((20 * 2 + 0) * 64 + lane) * 16);
        const short8v a1 = *(const short8v*)(lds + ((20 * 2 + 1) * 64 + lane) * 16);
        __builtin_amdgcn_s_setprio(1);
        acc0[0] = MFMA16x32(a0, cur0, acc0[0]);
        acc1[0] = MFMA16x32(a1, cur0, acc1[0]);
        acc0[1] = MFMA16x32(a0, cur1, acc0[1]);
        acc1[1] = MFMA16x32(a1, cur1, acc1[1]);
        acc0[2] = MFMA16x32(a0, cur2, acc0[2]);
        acc1[2] = MFMA16x32(a1, cur2, acc1[2]);
        __builtin_amdgcn_s_setprio(0);
    }
    #undef BLOAD
    __syncthreads();

    // ---- epilogue: gate -> unorm16 LDS, h -> hfrag bf16 (fast GELU) ----
    #pragma unroll
    for (int q = 0; q < 3; ++q) {
        const int e = (ng * 3 + q) * 16 + col;
        #pragma unroll
        for (int j = 0; j < 4; ++j) {
            #pragma unroll
            for (int mi = 0; mi < 2; ++mi) {
                const float vv = (mi == 0) ? acc0[q][j] : acc1[q][j];
                const int token = mi * 16 + rg * 4 + j;
                if (e < 128) {
                    const float gv = 1.f / (1.f + __expf(-vv));
                    gateb[token * 128 + e] = (unsigned short)(gv * 65535.f + 0.5f);
                } else {
                    const int rr = e - 128;
                    const float hv = gelu_f(vv);
                    hfrag[mi * 4096 + (rr >> 5) * 512 + (rg * 4 + j + 16 * ((rr >> 3) & 3)) * 8 + (rr & 7)] = f2bf(hv);
                }
            }
        }
    }
    __syncthreads();

    // ---- proj2 distributed over all 8 waves ----
    {
        const int mm = wid & 1, nh = wid >> 1;
        float4v y[2];
        float lg[2], lb[2];
        #pragma unroll
        for (int nti = 0; nti < 2; ++nti) {
            const int i = (nh * 2 + nti) * 16 + col;
            const float b = p2b[i];
            y[nti] = float4v{b, b, b, b};
            lg[nti] = lng[i];
            lb[nti] = lnb[i];
        }
        #pragma unroll
        for (int ks = 0; ks < 8; ++ks) {
            const short8v ah = *(const short8v*)(hfrag + mm * 4096 + ks * 512 + lane * 8);
            #pragma unroll
            for (int nti = 0; nti < 2; ++nti) {
                const short8v bw = *(const short8v*)(p2frag + (((nh * 2 + nti) * 8 + ks) * 64 + lane) * 8);
                y[nti] = MFMA16x32(ah, bw, y[nti]);
            }
        }
        #pragma unroll
        for (int j = 0; j < 4; ++j) {
            const int token = mm * 16 + rg * 4 + j;
            float s = y[0][j] + y[1][j];
            float qq = y[0][j] * y[0][j] + y[1][j] * y[1][j];
            s  += __shfl_xor(s, 1);  s  += __shfl_xor(s, 2);
            s  += __shfl_xor(s, 4);  s  += __shfl_xor(s, 8);
            qq += __shfl_xor(qq, 1); qq += __shfl_xor(qq, 2);
            qq += __shfl_xor(qq, 4); qq += __shfl_xor(qq, 8);
            if (col == 0) {
                lnp[token * 8 + nh * 2]     = s;
                lnp[token * 8 + nh * 2 + 1] = qq;
            }
        }
        __syncthreads();
        #pragma unroll
        for (int j = 0; j < 4; ++j) {
            const int token = mm * 16 + rg * 4 + j;
            const float s  = lnp[token * 8] + lnp[token * 8 + 2] + lnp[token * 8 + 4] + lnp[token * 8 + 6];
            const float qq = lnp[token * 8 + 1] + lnp[token * 8 + 3] + lnp[token * 8 + 5] + lnp[token * 8 + 7];
            const float mu = s * (1.f / 128.f);
            const float var = qq * (1.f / 128.f) - mu * mu;
            const float inv = rsqrtf(var + LN_EPS);
            float* op = out + (size_t)(n0 + token) * 128;
            #pragma unroll
            for (int nti = 0; nti < 2; ++nti) {
                const int i = (nh * 2 + nti) * 16 + col;
                const float gv = (float)gateb[token * 128 + i] * (1.f / 65535.f);
                op[i] = ((y[nti][j] - mu) * inv * lg[nti] + lb[nti]) * gv;
            }
        }
    }
}

extern "C" void kernel_launch(void* const* d_in, const int* in_sizes, int n_in,
                              void* d_out, int out_size, void* d_ws, size_t ws_size,
                              hipStream_t stream)
{
    const float* x          = (const float*)d_in[0];
    const float* band_W     = (const float*)d_in[1];
    const float* band_b     = (const float*)d_in[2];
    const float* freq_pos   = (const float*)d_in[3];
    const float* in_proj_w  = (const float*)d_in[4];
    const float* in_proj_b  = (const float*)d_in[5];
    const float* out_proj_w = (const float*)d_in[6];
    const float* out_proj_b = (const float*)d_in[7];
    const float* gate_w     = (const float*)d_in[8];
    const float* gate_b     = (const float*)d_in[9];
    const float* proj1_w    = (const float*)d_in[10];
    const float* proj1_b    = (const float*)d_in[11];
    const float* proj2_w    = (const float*)d_in[12];
    const float* proj2_b    = (const float*)d_in[13];
    const float* ln_g       = (const float*)d_in[14];
    const float* ln_b       = (const float*)d_in[15];
    float* outp = (float*)d_out;

    float* wsf = (float*)d_ws;
    unsigned short* p2f = (unsigned short*)((char*)d_ws + P2F_B);
    unsigned short* wta = (unsigned short*)((char*)d_ws + WTA_B);

    const int Ntok = in_sizes[0] / FB;   // 32768
    const int nblk = Ntok / 32;          // 1024

    hipLaunchKernelGGL(precompK1, dim3(NB_ACO + NB_BIAS + NB_P2), dim3(512), 0, stream,
                       band_W, band_b, freq_pos, in_proj_w, in_proj_b, out_proj_w,
                       gate_w, gate_b, proj1_w, proj1_b, out_proj_b, proj2_w, p2f, wsf);
    hipLaunchKernelGGL(precompK2, dim3(NB_WTA + 1), dim3(512), 0, stream,
                       gate_w, proj1_w, wsf, wta, wsf);
    hipLaunchKernelGGL(fba_main,  dim3(nblk), dim3(NT), 0, stream,
                       x, proj2_b, ln_g, ln_b, wsf, p2f, wta, outp);
}